// Round 4
// baseline (167.017 us; speedup 1.0000x reference)
//
#include <hip/hip_runtime.h>

#define B 64
#define N 4096
#define M 128

constexpr int T    = 512;      // 8 waves
constexpr int CPB  = 4;        // 4 real channels -> 2 packed complex FFTs (a,b)
constexpr int NB_M = M / CPB;  // 32
constexpr int NWG  = B * NB_M; // 2048

// XOR-fold high bits into low 4: spreads strided butterfly patterns across bank pairs.
__device__ __forceinline__ int sw(int p) {
    return (p & ~15) | ((p ^ (p >> 4) ^ (p >> 8)) & 15);
}

__device__ __forceinline__ float2 cadd(float2 a, float2 b){ return make_float2(a.x+b.x, a.y+b.y); }
__device__ __forceinline__ float2 csub(float2 a, float2 b){ return make_float2(a.x-b.x, a.y-b.y); }
__device__ __forceinline__ float2 cmul(float2 a, float2 b){ return make_float2(a.x*b.x - a.y*b.y, a.x*b.y + a.y*b.x); }
__device__ __forceinline__ float2 mulnegi(float2 a){ return make_float2(a.y, -a.x); }
__device__ __forceinline__ float2 muli(float2 a)  { return make_float2(-a.y, a.x); }

// forward DFT8 in place (W8 = e^{-i pi/4})
__device__ __forceinline__ void dft8(float2 t[8]) {
    float2 e0=cadd(t[0],t[4]), e1=csub(t[0],t[4]);
    float2 e2=cadd(t[2],t[6]), e3=csub(t[2],t[6]);
    float2 E0=cadd(e0,e2), E2=csub(e0,e2);
    float2 E1=cadd(e1,mulnegi(e3)), E3=cadd(e1,muli(e3));
    float2 o0=cadd(t[1],t[5]), o1=csub(t[1],t[5]);
    float2 o2=cadd(t[3],t[7]), o3=csub(t[3],t[7]);
    float2 O0=cadd(o0,o2), O2=csub(o0,o2);
    float2 O1=cadd(o1,mulnegi(o3)), O3=cadd(o1,muli(o3));
    const float C = 0.70710678118654752f;
    float2 w1O1 = make_float2(C*(O1.x+O1.y), C*(O1.y-O1.x));
    float2 w2O2 = mulnegi(O2);
    float2 w3O3 = make_float2(C*(O3.y-O3.x), -C*(O3.x+O3.y));
    t[0]=cadd(E0,O0);   t[4]=csub(E0,O0);
    t[1]=cadd(E1,w1O1); t[5]=csub(E1,w1O1);
    t[2]=cadd(E2,w2O2); t[6]=csub(E2,w2O2);
    t[3]=cadd(E3,w3O3); t[7]=csub(E3,w3O3);
}

// twiddle legs k=1..7 by W^(j*k), W = cis(-2pi*j/den), applied to both FFTs, then dft8
__device__ __forceinline__ void twiddle_dft8(float2 a[8], float2 b[8], int j, float invDen) {
    float sn, cs;
    __sincosf(-6.2831853071795864f * (float)j * invDen, &sn, &cs);
    float2 w1 = make_float2(cs, sn);
    float2 w = w1;
    #pragma unroll
    for (int k = 1; k < 8; ++k) {
        a[k] = cmul(a[k], w);
        b[k] = cmul(b[k], w);
        w = cmul(w, w1);
    }
    dft8(a);
    dft8(b);
}

__global__ __launch_bounds__(T, 6)
void FFTlayer_52699248722191_kernel(const float* __restrict__ x, float* __restrict__ out) {
    __shared__ float2 xch[N];   // 32 KiB exchange buffer (shared A-then-B)

    int bid = blockIdx.x;
    int swz = (bid & 7) * (NWG / 8) + (bid >> 3);   // XCD-chunked swizzle
    int b   = swz / NB_M;
    int m0  = (swz % NB_M) * CPB;

    const float* xb = x + (size_t)b * N * M + m0;
    const int t = threadIdx.x;

    float2 a[8], bb[8];

    // ---- gather (4-octal-digit reversed) + stage 1 (L=1, no twiddle) ----
    {
        const int c = ((t & 7) << 6) | (t & 56) | (t >> 6);  // rev3 of 9-bit t
        #pragma unroll
        for (int k = 0; k < 8; ++k) {
            float4 v = *(const float4*)(xb + (size_t)(k * 512 + c) * M);
            a[k]  = make_float2(v.x, v.y);
            bb[k] = make_float2(v.z, v.w);
        }
        dft8(a);
        dft8(bb);
    }

    // positions after stage s: stage1 p=8t+k; stage2 base=(t>>3)*64+(t&7), +8k;
    // stage3 base=(t>>6)*512+(t&63), +64k; stage4 base=t, +512k.
    const int p1 = 8 * t;
    const int b2 = ((t >> 3) << 6) | (t & 7);
    const int b3 = ((t >> 6) << 9) | (t & 63);

    // ---- exchange 1 -> stage 2 (j = t&7, den 64) ----
    #pragma unroll
    for (int k = 0; k < 8; ++k) xch[sw(p1 + k)] = a[k];
    __syncthreads();
    #pragma unroll
    for (int k = 0; k < 8; ++k) a[k] = xch[sw(b2 + (k << 3))];
    __syncthreads();
    #pragma unroll
    for (int k = 0; k < 8; ++k) xch[sw(p1 + k)] = bb[k];
    __syncthreads();
    #pragma unroll
    for (int k = 0; k < 8; ++k) bb[k] = xch[sw(b2 + (k << 3))];
    __syncthreads();
    twiddle_dft8(a, bb, t & 7, 1.0f / 64.0f);

    // ---- exchange 2 -> stage 3 (j = t&63, den 512) ----
    #pragma unroll
    for (int k = 0; k < 8; ++k) xch[sw(b2 + (k << 3))] = a[k];
    __syncthreads();
    #pragma unroll
    for (int k = 0; k < 8; ++k) a[k] = xch[sw(b3 + (k << 6))];
    __syncthreads();
    #pragma unroll
    for (int k = 0; k < 8; ++k) xch[sw(b2 + (k << 3))] = bb[k];
    __syncthreads();
    #pragma unroll
    for (int k = 0; k < 8; ++k) bb[k] = xch[sw(b3 + (k << 6))];
    __syncthreads();
    twiddle_dft8(a, bb, t & 63, 1.0f / 512.0f);

    // ---- exchange 3 -> stage 4 (j = t, den 4096) ----
    #pragma unroll
    for (int k = 0; k < 8; ++k) xch[sw(b3 + (k << 6))] = a[k];
    __syncthreads();
    #pragma unroll
    for (int k = 0; k < 8; ++k) a[k] = xch[sw(t + (k << 9))];
    __syncthreads();
    #pragma unroll
    for (int k = 0; k < 8; ++k) xch[sw(b3 + (k << 6))] = bb[k];
    __syncthreads();
    #pragma unroll
    for (int k = 0; k < 8; ++k) bb[k] = xch[sw(t + (k << 9))];
    __syncthreads();
    twiddle_dft8(a, bb, t, 1.0f / 4096.0f);
    // now a[k] = Z_A[t + 512k], bb[k] = Z_B[t + 512k]  (natural order)

    // ---- Hermitian unpack + merged float4 stores ----
    float* outRe = out;
    float* outIm = out + (size_t)B * N * M;
    const size_t rowBase = (size_t)b * N * M + m0;

    // A: stash spectrum in LDS, read partner rows, hold unpacked A in regs
    #pragma unroll
    for (int k = 0; k < 8; ++k) xch[sw(t + (k << 9))] = a[k];
    __syncthreads();
    float reA0[8], reA1[8], imA0[8], imA1[8];
    #pragma unroll
    for (int k = 0; k < 8; ++k) {
        int row  = t + (k << 9);
        int mrow = (N - row) & (N - 1);
        float2 Zk = a[k];
        float2 Zm = xch[sw(mrow)];
        reA0[k] = 0.5f * (Zk.x + Zm.x);
        imA0[k] = 0.5f * (Zk.y - Zm.y);
        reA1[k] = 0.5f * (Zk.y + Zm.y);
        imA1[k] = 0.5f * (Zm.x - Zk.x);
    }
    __syncthreads();
    // B: same, merge with A and store
    #pragma unroll
    for (int k = 0; k < 8; ++k) xch[sw(t + (k << 9))] = bb[k];
    __syncthreads();
    #pragma unroll
    for (int k = 0; k < 8; ++k) {
        int row  = t + (k << 9);
        int mrow = (N - row) & (N - 1);
        float2 Zk = bb[k];
        float2 Zm = xch[sw(mrow)];
        float4 re, im;
        re.x = reA0[k]; re.y = reA1[k];
        im.x = imA0[k]; im.y = imA1[k];
        re.z = 0.5f * (Zk.x + Zm.x);
        im.z = 0.5f * (Zk.y - Zm.y);
        re.w = 0.5f * (Zk.y + Zm.y);
        im.w = 0.5f * (Zm.x - Zk.x);
        *(float4*)(outRe + rowBase + (size_t)row * M) = re;
        *(float4*)(outIm + rowBase + (size_t)row * M) = im;
    }
}

extern "C" void kernel_launch(void* const* d_in, const int* in_sizes, int n_in,
                              void* d_out, int out_size, void* d_ws, size_t ws_size,
                              hipStream_t stream) {
    const float* x = (const float*)d_in[0];
    float* out = (float*)d_out;
    FFTlayer_52699248722191_kernel<<<NWG, T, 0, stream>>>(x, out);
}

// Round 5
// 150.679 us; speedup vs baseline: 1.1084x; 1.1084x over previous
//
#include <hip/hip_runtime.h>

#define B 64
#define N 4096
#define M 128

__device__ __forceinline__ float2 cadd(float2 a, float2 b){ return make_float2(a.x+b.x, a.y+b.y); }
__device__ __forceinline__ float2 csub(float2 a, float2 b){ return make_float2(a.x-b.x, a.y-b.y); }
__device__ __forceinline__ float2 cmul(float2 a, float2 b){ return make_float2(a.x*b.x - a.y*b.y, a.x*b.y + a.y*b.x); }
__device__ __forceinline__ float2 mulnegi(float2 a){ return make_float2(a.y, -a.x); }
__device__ __forceinline__ float2 muli(float2 a)  { return make_float2(-a.y, a.x); }
__device__ __forceinline__ float2 cis(float ang){ float s, c; __sincosf(ang, &s, &c); return make_float2(c, s); }

// forward DFT8 in place (W8 = e^{-i pi/4}): t_out[k] = sum_c t_in[c] W8^{ck}
__device__ __forceinline__ void dft8(float2 t[8]) {
    float2 e0=cadd(t[0],t[4]), e1=csub(t[0],t[4]);
    float2 e2=cadd(t[2],t[6]), e3=csub(t[2],t[6]);
    float2 E0=cadd(e0,e2), E2=csub(e0,e2);
    float2 E1=cadd(e1,mulnegi(e3)), E3=cadd(e1,muli(e3));
    float2 o0=cadd(t[1],t[5]), o1=csub(t[1],t[5]);
    float2 o2=cadd(t[3],t[7]), o3=csub(t[3],t[7]);
    float2 O0=cadd(o0,o2), O2=csub(o0,o2);
    float2 O1=cadd(o1,mulnegi(o3)), O3=cadd(o1,muli(o3));
    const float C = 0.70710678118654752f;
    float2 w1O1 = make_float2(C*(O1.x+O1.y), C*(O1.y-O1.x));
    float2 w2O2 = mulnegi(O2);
    float2 w3O3 = make_float2(C*(O3.y-O3.x), -C*(O3.x+O3.y));
    t[0]=cadd(E0,O0);   t[4]=csub(E0,O0);
    t[1]=cadd(E1,w1O1); t[5]=csub(E1,w1O1);
    t[2]=cadd(E2,w2O2); t[6]=csub(E2,w2O2);
    t[3]=cadd(E3,w3O3); t[7]=csub(E3,w3O3);
}

// ============ four-step: N = 64 x 64, n = 64*n1 + n2, k = 64*k2 + k1 ============
// K1: A[b][k1][n2][mc] = FFT64_{n1}( x[b][64n1+n2][2mc..2mc+1 packed] ) * W4096^{n2*k1}
// K2: Z[b][64k2+k1][mc] = FFT64_{n2}( A[b][k1][n2][mc] ), then Hermitian unpack.

__global__ __launch_bounds__(512, 4)
void fft_k1(const float* __restrict__ x, float2* __restrict__ ws) {
    __shared__ float2 z[64][64];     // [n1][mc], 32 KiB
    const int bid = blockIdx.x;
    const int b = bid >> 6, n2 = bid & 63;
    const float* xb = x + (size_t)b*(N*M) + (size_t)n2*M;
    const int t = threadIdx.x;

    // coalesced load: 64 rows (n1) x 512B; pack channel pairs into complex
    #pragma unroll
    for (int j = 0; j < 4; ++j) {
        int i = t + (j << 9);                 // 0..2047 float4 index
        int n1 = i >> 5, q = i & 31;
        float4 v = *(const float4*)(xb + (size_t)n1*(64*M) + (q << 2));
        z[n1][2*q]   = make_float2(v.x, v.y);
        z[n1][2*q+1] = make_float2(v.z, v.w);
    }
    __syncthreads();

    const int mc = t & 63, g = t >> 6;        // lane = mc -> LDS conflict-free
    float2 r[8];
    // stage 1: a = g, legs n1 = g + 8c (no twiddle)
    #pragma unroll
    for (int c = 0; c < 8; ++c) r[c] = z[g + (c<<3)][mc];
    dft8(r);
    #pragma unroll
    for (int k = 0; k < 8; ++k) z[g + (k<<3)][mc] = r[k];
    __syncthreads();
    // stage 2: k1lo = g, legs at slot a + 8g hold G[a][g]
    #pragma unroll
    for (int a = 0; a < 8; ++a) r[a] = z[a + (g<<3)][mc];
    {
        float2 w1 = cis(-6.2831853071795864f * (float)g / 64.0f);
        float2 w = w1;
        #pragma unroll
        for (int a = 1; a < 8; ++a) { r[a] = cmul(r[a], w); w = cmul(w, w1); }
    }
    dft8(r);                                   // r[k2i] = X64[8*k2i + g]
    // global twiddle W4096^{n2*k1} + coalesced store (512B per k1 chunk)
    const float base = -6.2831853071795864f * (float)n2;
    float2 wcur  = cis(base * (float)g / 4096.0f);
    const float2 wstep = cis(base / 512.0f);
    float2* wsp = ws + ((size_t)b << 18) + ((size_t)n2 << 6) + mc;   // [b][k1][n2][mc]
    #pragma unroll
    for (int k2i = 0; k2i < 8; ++k2i) {
        int k1 = (k2i << 3) + g;
        wsp[(size_t)k1 << 12] = cmul(r[k2i], wcur);
        wcur = cmul(wcur, wstep);
    }
}

__global__ __launch_bounds__(512, 2)
void fft_k2(const float2* __restrict__ ws, float* __restrict__ out) {
    __shared__ float2 z2[2][64][64];   // [set][k2/n2][mc swizzled], 64 KiB
    const int bid = blockIdx.x;
    const int b = bid >> 5, p = bid & 31;
    const int t = threadIdx.x;
    int k1s[2];
    if (p == 0) { k1s[0] = 0; k1s[1] = 32; } else { k1s[0] = p; k1s[1] = 64 - p; }

    // load: per set one contiguous 32KB slab; XOR-swizzle mc by (row & 15)
    #pragma unroll
    for (int s = 0; s < 2; ++s) {
        const float4* src = (const float4*)(ws + ((size_t)((b << 6) + k1s[s]) << 12));
        #pragma unroll
        for (int j = 0; j < 4; ++j) {
            int i = t + (j << 9);             // 0..2047 float4
            float4 v = src[i];
            int n2 = i >> 5, q = i & 31, sh = n2 & 15;
            z2[s][n2][(2*q) ^ sh]   = make_float2(v.x, v.y);
            z2[s][n2][(2*q+1) ^ sh] = make_float2(v.z, v.w);
        }
    }
    __syncthreads();

    const int mc = t & 63, g = t >> 6;
    // stage 1 per set (in place, disjoint slots per thread)
    #pragma unroll
    for (int s = 0; s < 2; ++s) {
        float2 r[8];
        #pragma unroll
        for (int c = 0; c < 8; ++c) { int row = g + (c<<3); r[c] = z2[s][row][mc ^ (row & 15)]; }
        dft8(r);
        #pragma unroll
        for (int k = 0; k < 8; ++k) { int row = g + (k<<3); z2[s][row][mc ^ (row & 15)] = r[k]; }
    }
    __syncthreads();
    // stage 2 into registers for both sets
    float2 X[2][8];
    {
        float2 w1 = cis(-6.2831853071795864f * (float)g / 64.0f);
        #pragma unroll
        for (int s = 0; s < 2; ++s) {
            float2 r[8];
            #pragma unroll
            for (int a = 0; a < 8; ++a) { int row = a + (g<<3); r[a] = z2[s][row][mc ^ (row & 15)]; }
            float2 w = w1;
            #pragma unroll
            for (int a = 1; a < 8; ++a) { r[a] = cmul(r[a], w); w = cmul(w, w1); }
            dft8(r);
            #pragma unroll
            for (int k = 0; k < 8; ++k) X[s][k] = r[k];
        }
    }
    __syncthreads();
    // write spectra back by k2
    #pragma unroll
    for (int s = 0; s < 2; ++s) {
        #pragma unroll
        for (int k = 0; k < 8; ++k) { int k2 = (k<<3) + g; z2[s][k2][mc ^ (k2 & 15)] = X[s][k]; }
    }
    __syncthreads();

    // Hermitian unpack + fully-coalesced stores (full 512B rows per block)
    float* outRe = out;
    float* outIm = out + (size_t)B * N * M;
    const int rr = t >> 2;            // 0..127 row slot (2 sets x 64 k2)
    const int s  = rr >> 6;
    const int k2 = rr & 63;
    const int k1 = k1s[s];
    int sp, k2p;
    if (p == 0) { sp = s; k2p = (s == 0) ? ((64 - k2) & 63) : (63 - k2); }
    else        { sp = 1 - s; k2p = 63 - k2; }
    const int krow = (k2 << 6) + k1;
    const size_t rbase = (size_t)b*(N*M) + (size_t)krow*M;
    #pragma unroll
    for (int j = 0; j < 8; ++j) {
        int q = (t & 3) + (j << 2);   // 0..31 float4 within row
        float2 Zk0 = z2[s ][k2 ][(2*q)   ^ (k2  & 15)];
        float2 Zk1 = z2[s ][k2 ][(2*q+1) ^ (k2  & 15)];
        float2 Zm0 = z2[sp][k2p][(2*q)   ^ (k2p & 15)];
        float2 Zm1 = z2[sp][k2p][(2*q+1) ^ (k2p & 15)];
        float4 re, im;
        re.x = 0.5f*(Zk0.x + Zm0.x); im.x = 0.5f*(Zk0.y - Zm0.y);
        re.y = 0.5f*(Zk0.y + Zm0.y); im.y = 0.5f*(Zm0.x - Zk0.x);
        re.z = 0.5f*(Zk1.x + Zm1.x); im.z = 0.5f*(Zk1.y - Zm1.y);
        re.w = 0.5f*(Zk1.y + Zm1.y); im.w = 0.5f*(Zm1.x - Zk1.x);
        *(float4*)(outRe + rbase + (q << 2)) = re;
        *(float4*)(outIm + rbase + (q << 2)) = im;
    }
}

// ================= fallback (round-3 single-kernel, if ws too small) =================
constexpr int FT    = 512;
constexpr int FCPB  = 4;
constexpr int FNB_M = M / FCPB;
constexpr int FNWG  = B * FNB_M;

__device__ __forceinline__ int swf(int p) {
    return (p & ~15) | ((p ^ (p >> 4) ^ (p >> 8)) & 15);
}
__device__ __forceinline__ void twiddle_dft8(float2 a[8], float2 b[8], int j, float invDen) {
    float2 w1 = cis(-6.2831853071795864f * (float)j * invDen);
    float2 w = w1;
    #pragma unroll
    for (int k = 1; k < 8; ++k) {
        a[k] = cmul(a[k], w);
        b[k] = cmul(b[k], w);
        w = cmul(w, w1);
    }
    dft8(a);
    dft8(b);
}

__global__ __launch_bounds__(FT, 6)
void fft_fallback(const float* __restrict__ x, float* __restrict__ out) {
    __shared__ float2 xch[N];
    int bid = blockIdx.x;
    int swz = (bid & 7) * (FNWG / 8) + (bid >> 3);
    int b   = swz / FNB_M;
    int m0  = (swz % FNB_M) * FCPB;
    const float* xb = x + (size_t)b * N * M + m0;
    const int t = threadIdx.x;
    float2 a[8], bb[8];
    {
        const int c = ((t & 7) << 6) | (t & 56) | (t >> 6);
        #pragma unroll
        for (int k = 0; k < 8; ++k) {
            float4 v = *(const float4*)(xb + (size_t)(k * 512 + c) * M);
            a[k]  = make_float2(v.x, v.y);
            bb[k] = make_float2(v.z, v.w);
        }
        dft8(a); dft8(bb);
    }
    const int p1 = 8 * t;
    const int b2 = ((t >> 3) << 6) | (t & 7);
    const int b3 = ((t >> 6) << 9) | (t & 63);
    #pragma unroll
    for (int k = 0; k < 8; ++k) xch[swf(p1 + k)] = a[k];
    __syncthreads();
    #pragma unroll
    for (int k = 0; k < 8; ++k) a[k] = xch[swf(b2 + (k << 3))];
    __syncthreads();
    #pragma unroll
    for (int k = 0; k < 8; ++k) xch[swf(p1 + k)] = bb[k];
    __syncthreads();
    #pragma unroll
    for (int k = 0; k < 8; ++k) bb[k] = xch[swf(b2 + (k << 3))];
    __syncthreads();
    twiddle_dft8(a, bb, t & 7, 1.0f / 64.0f);
    #pragma unroll
    for (int k = 0; k < 8; ++k) xch[swf(b2 + (k << 3))] = a[k];
    __syncthreads();
    #pragma unroll
    for (int k = 0; k < 8; ++k) a[k] = xch[swf(b3 + (k << 6))];
    __syncthreads();
    #pragma unroll
    for (int k = 0; k < 8; ++k) xch[swf(b2 + (k << 3))] = bb[k];
    __syncthreads();
    #pragma unroll
    for (int k = 0; k < 8; ++k) bb[k] = xch[swf(b3 + (k << 6))];
    __syncthreads();
    twiddle_dft8(a, bb, t & 63, 1.0f / 512.0f);
    #pragma unroll
    for (int k = 0; k < 8; ++k) xch[swf(b3 + (k << 6))] = a[k];
    __syncthreads();
    #pragma unroll
    for (int k = 0; k < 8; ++k) a[k] = xch[swf(t + (k << 9))];
    __syncthreads();
    #pragma unroll
    for (int k = 0; k < 8; ++k) xch[swf(b3 + (k << 6))] = bb[k];
    __syncthreads();
    #pragma unroll
    for (int k = 0; k < 8; ++k) bb[k] = xch[swf(t + (k << 9))];
    __syncthreads();
    twiddle_dft8(a, bb, t, 1.0f / 4096.0f);
    float* outRe = out;
    float* outIm = out + (size_t)B * N * M;
    const size_t rowBase = (size_t)b * N * M + m0;
    #pragma unroll
    for (int k = 0; k < 8; ++k) xch[swf(t + (k << 9))] = a[k];
    __syncthreads();
    float reA0[8], reA1[8], imA0[8], imA1[8];
    #pragma unroll
    for (int k = 0; k < 8; ++k) {
        int row  = t + (k << 9);
        int mrow = (N - row) & (N - 1);
        float2 Zk = a[k];
        float2 Zm = xch[swf(mrow)];
        reA0[k] = 0.5f * (Zk.x + Zm.x);
        imA0[k] = 0.5f * (Zk.y - Zm.y);
        reA1[k] = 0.5f * (Zk.y + Zm.y);
        imA1[k] = 0.5f * (Zm.x - Zk.x);
    }
    __syncthreads();
    #pragma unroll
    for (int k = 0; k < 8; ++k) xch[swf(t + (k << 9))] = bb[k];
    __syncthreads();
    #pragma unroll
    for (int k = 0; k < 8; ++k) {
        int row  = t + (k << 9);
        int mrow = (N - row) & (N - 1);
        float2 Zk = bb[k];
        float2 Zm = xch[swf(mrow)];
        float4 re, im;
        re.x = reA0[k]; re.y = reA1[k];
        im.x = imA0[k]; im.y = imA1[k];
        re.z = 0.5f * (Zk.x + Zm.x);
        im.z = 0.5f * (Zk.y - Zm.y);
        re.w = 0.5f * (Zk.y + Zm.y);
        im.w = 0.5f * (Zm.x - Zk.x);
        *(float4*)(outRe + rowBase + (size_t)row * M) = re;
        *(float4*)(outIm + rowBase + (size_t)row * M) = im;
    }
}

extern "C" void kernel_launch(void* const* d_in, const int* in_sizes, int n_in,
                              void* d_out, int out_size, void* d_ws, size_t ws_size,
                              hipStream_t stream) {
    const float* x = (const float*)d_in[0];
    float* out = (float*)d_out;
    const size_t ws_needed = (size_t)B * 64 * 64 * 64 * sizeof(float2);  // 134 MB
    if (ws_size >= ws_needed) {
        float2* ws = (float2*)d_ws;
        fft_k1<<<B * 64, 512, 0, stream>>>(x, ws);
        fft_k2<<<B * 32, 512, 0, stream>>>(ws, out);
    } else {
        fft_fallback<<<FNWG, FT, 0, stream>>>(x, out);
    }
}

// Round 6
// 146.057 us; speedup vs baseline: 1.1435x; 1.0316x over previous
//
#include <hip/hip_runtime.h>
#include <hip/hip_fp16.h>

#define B 64
#define N 4096
#define M 128

constexpr int T    = 1024;          // 16 waves, 1 block/CU (128 KiB LDS)
constexpr int CPB  = 16;            // channels/block -> 8 packed complex FFTs
constexpr int NF   = 8;
constexpr int NWG  = B * (M / CPB); // 512 blocks = exactly 2 rounds over 256 CUs

// 5-bit XOR fold: spreads strided butterfly legs across the 32 LDS banks.
// Bijective within [0,4096).
__device__ __forceinline__ int fold5(int p) {
    return (p & ~31) | ((p ^ (p >> 5) ^ (p >> 9)) & 31);
}
// octal-digit reverse of 12-bit index (DIF output slot of frequency k)
__device__ __forceinline__ int rev12(int k) {
    return ((k & 7) << 9) | (((k >> 3) & 7) << 6) | (((k >> 6) & 7) << 3) | ((k >> 9) & 7);
}

__device__ __forceinline__ float2 cadd(float2 a, float2 b){ return make_float2(a.x+b.x, a.y+b.y); }
__device__ __forceinline__ float2 csub(float2 a, float2 b){ return make_float2(a.x-b.x, a.y-b.y); }
__device__ __forceinline__ float2 cmul(float2 a, float2 b){ return make_float2(a.x*b.x - a.y*b.y, a.x*b.y + a.y*b.x); }
__device__ __forceinline__ float2 mulnegi(float2 a){ return make_float2(a.y, -a.x); }
__device__ __forceinline__ float2 muli(float2 a)  { return make_float2(-a.y, a.x); }
__device__ __forceinline__ float2 cis(float ang){ float s, c; __sincosf(ang, &s, &c); return make_float2(c, s); }
__device__ __forceinline__ float2 h2f(__half2 h){ return __half22float2(h); }
__device__ __forceinline__ __half2 f2h(float2 v){ return __floats2half2_rn(v.x, v.y); }

// forward DFT8 in place (W8 = e^{-i pi/4}): t_out[k] = sum_c t_in[c] W8^{ck}
__device__ __forceinline__ void dft8(float2 t[8]) {
    float2 e0=cadd(t[0],t[4]), e1=csub(t[0],t[4]);
    float2 e2=cadd(t[2],t[6]), e3=csub(t[2],t[6]);
    float2 E0=cadd(e0,e2), E2=csub(e0,e2);
    float2 E1=cadd(e1,mulnegi(e3)), E3=cadd(e1,muli(e3));
    float2 o0=cadd(t[1],t[5]), o1=csub(t[1],t[5]);
    float2 o2=cadd(t[3],t[7]), o3=csub(t[3],t[7]);
    float2 O0=cadd(o0,o2), O2=csub(o0,o2);
    float2 O1=cadd(o1,mulnegi(o3)), O3=cadd(o1,muli(o3));
    const float C = 0.70710678118654752f;
    float2 w1O1 = make_float2(C*(O1.x+O1.y), C*(O1.y-O1.x));
    float2 w2O2 = mulnegi(O2);
    float2 w3O3 = make_float2(C*(O3.y-O3.x), -C*(O3.x+O3.y));
    t[0]=cadd(E0,O0);   t[4]=csub(E0,O0);
    t[1]=cadd(E1,w1O1); t[5]=csub(E1,w1O1);
    t[2]=cadd(E2,w2O2); t[6]=csub(E2,w2O2);
    t[3]=cadd(E3,w3O3); t[7]=csub(E3,w3O3);
}

// One radix-8 DIF stage, span S. In-place on identical slots per task ->
// barriers only between stages. out[r] = W_{8S}^{j r} * DFT8(t)[r].
template<int S>
__device__ __forceinline__ void stage(__half2* z, int tid) {
    #pragma unroll
    for (int it = 0; it < 4; ++it) {
        const int q  = tid + (it << 10);   // 0..4095
        const int f  = q >> 9;             // FFT id 0..7
        const int qq = q & 511;
        int G, j;
        if      (S == 512) { G = 0;                j = qq;      }
        else if (S == 64)  { G = (qq >> 6) << 9;   j = qq & 63; }
        else if (S == 8)   { G = (qq >> 3) << 6;   j = qq & 7;  }
        else               { G = qq << 3;          j = 0;       }
        const int nbase = G + j;
        const int fb = f << 12;
        int idx[8];
        #pragma unroll
        for (int c = 0; c < 8; ++c) idx[c] = fb + fold5(nbase + c * S);
        float2 r[8];
        #pragma unroll
        for (int c = 0; c < 8; ++c) r[c] = h2f(z[idx[c]]);
        dft8(r);
        if (S > 1) {
            float2 w1 = cis(-6.2831853071795864f * (float)j / (float)(8 * S));
            float2 w = w1;
            #pragma unroll
            for (int k = 1; k < 8; ++k) { r[k] = cmul(r[k], w); w = cmul(w, w1); }
        }
        #pragma unroll
        for (int c = 0; c < 8; ++c) z[idx[c]] = f2h(r[c]);
    }
}

__global__ __launch_bounds__(T, 4)
void fft_one(const float* __restrict__ x, float* __restrict__ out) {
    extern __shared__ __half2 z[];   // [NF][4096] bank-folded, 128 KiB
    const int bid = blockIdx.x;
    const int b = bid >> 3, mg = bid & 7;
    const int m0 = mg * CPB;
    const float* xb = x + (size_t)b * N * M + m0;
    const int tid = threadIdx.x;

    // ---- coalesced load: 4096 rows x 64B (16 ch); pack ch pairs as half2 cplx ----
    #pragma unroll
    for (int it = 0; it < 16; ++it) {
        int i = tid + (it << 10);          // 0..16383 float4 tasks
        int n = i >> 2, c = i & 3;
        float4 v = *(const float4*)(xb + (size_t)n * M + (c << 2));
        int fn = fold5(n);
        z[((2 * c)     << 12) + fn] = f2h(make_float2(v.x, v.y));
        z[((2 * c + 1) << 12) + fn] = f2h(make_float2(v.z, v.w));
    }
    __syncthreads();

    // ---- 4 radix-8 DIF stages: natural in -> digit-reversed out ----
    stage<512>(z, tid); __syncthreads();
    stage<64 >(z, tid); __syncthreads();
    stage<8  >(z, tid); __syncthreads();
    stage<1  >(z, tid); __syncthreads();

    // ---- Hermitian unpack (freq k at slot rev12(k)) + full-segment stores ----
    float* outRe = out;
    float* outIm = out + (size_t)B * N * M;
    const size_t rbase = (size_t)b * N * M + m0;
    #pragma unroll
    for (int it = 0; it < 16; ++it) {
        int u = tid + (it << 10);          // 0..16383 (row k, ch-quad c)
        int k = u >> 2, c = u & 3;
        int kk = (N - k) & (N - 1);
        int sk = fold5(rev12(k)), smk = fold5(rev12(kk));
        int f0 = (2 * c) << 12, f1 = (2 * c + 1) << 12;
        float2 Zk0 = h2f(z[f0 + sk]),  Zm0 = h2f(z[f0 + smk]);
        float2 Zk1 = h2f(z[f1 + sk]),  Zm1 = h2f(z[f1 + smk]);
        float4 re, im;
        re.x = 0.5f * (Zk0.x + Zm0.x); im.x = 0.5f * (Zk0.y - Zm0.y);
        re.y = 0.5f * (Zk0.y + Zm0.y); im.y = 0.5f * (Zm0.x - Zk0.x);
        re.z = 0.5f * (Zk1.x + Zm1.x); im.z = 0.5f * (Zk1.y - Zm1.y);
        re.w = 0.5f * (Zk1.y + Zm1.y); im.w = 0.5f * (Zm1.x - Zk1.x);
        *(float4*)(outRe + rbase + (size_t)k * M + (c << 2)) = re;
        *(float4*)(outIm + rbase + (size_t)k * M + (c << 2)) = im;
    }
}

extern "C" void kernel_launch(void* const* d_in, const int* in_sizes, int n_in,
                              void* d_out, int out_size, void* d_ws, size_t ws_size,
                              hipStream_t stream) {
    const float* x = (const float*)d_in[0];
    float* out = (float*)d_out;
    const int lds_bytes = NF * N * (int)sizeof(__half2);   // 131072
    hipFuncSetAttribute((const void*)fft_one,
                        hipFuncAttributeMaxDynamicSharedMemorySize, lds_bytes);
    fft_one<<<NWG, T, lds_bytes, stream>>>(x, out);
}